// Round 20
// baseline (208.628 us; speedup 1.0000x reference)
//
#include <hip/hip_runtime.h>

// Problem: nearest = memory[argmax_m cosine(x_row, memory_m)], plus copy of x.
//   x: 65536 x 1024 f32, memory: 40 x 1024 f32, out = [nearest | x-copy]
//
// R20 = R19 (188us) with staged chunk K/4 -> K/8: 16 rows x 128 floats
// (512B/row-instruction, 4 full lines), LDS 8KB/wave -> 32KB/block ->
// 4 blocks/CU (launch_bounds(256,4), VGPR ~100) = 4 waves/SIMD (was 2).
// Theory: residual cost is one ~900cy HBM exposure per wave per chunk at
// consume; 2 waves/SIMD couldn't fill each other's stalls (R4's occupancy
// null was the barrier-convoy regime - untested here). 2x TLP should hide.
// Risk: contiguity 1KB->512B gives back some of R18's page-efficiency win.
//
// d_ws layout (bytes):
//   [0,      320) : double inv64[40]
//   [320,    480) : float  inv32[40]
//   [512,  16896) : uint flagbits[4096]  (16-bit mask per 16-row wave)
//   [32768,131072): ushort BH[32][48][32] (bf16 hi of mem*inv32, step-major)
//   [131072,229376): ushort BL[32][48][32] (bf16 lo, step-major)

#define DIM 1024
#define NMEM 40

typedef float  vf4 __attribute__((ext_vector_type(4)));
typedef float  vf2 __attribute__((ext_vector_type(2)));
typedef float  f4a __attribute__((ext_vector_type(4)));
typedef short  s8v __attribute__((ext_vector_type(8)));

union FragU { s8v v; unsigned int u[4]; };

constexpr float TAU = 2.5e-4f;   // normalized top-2 gap below which f64 re-resolve

// ---------------- Kernel 1: memory-row inverse norms (f32 + f64) ----------------
__global__ __launch_bounds__(64) void k_norms(const float* __restrict__ mem,
                                              double* __restrict__ inv64,
                                              float* __restrict__ inv32) {
  const int m = blockIdx.x;      // 40 blocks, 1 wave each
  const int lane = threadIdx.x;
  const float* __restrict__ row = mem + (size_t)m * DIM;
  double s = 0.0;
#pragma unroll
  for (int i = 0; i < DIM / 64; ++i) {
    double v = (double)row[lane + 64 * i];
    s = fma(v, v, s);
  }
#pragma unroll
  for (int off = 32; off > 0; off >>= 1) s += __shfl_xor(s, off, 64);
  if (lane == 0) {
    double n = sqrt(s);
    n = (n > 1e-8) ? n : 1e-8;
    inv64[m] = 1.0 / n;
    inv32[m] = (float)(1.0 / n);
  }
}

// ------------- Kernel 1b: split normalized memory -> step-major bf16 hi/lo -------------
__global__ __launch_bounds__(256) void k_prep(const float* __restrict__ mem,
                                              const float* __restrict__ inv32,
                                              unsigned short* __restrict__ BH,
                                              unsigned short* __restrict__ BL) {
  const int m = blockIdx.x;            // 0..47 (40 real + 8 zero-pad)
  const int k0 = threadIdx.x * 4;      // 1024/256 = 4 elems/thread
#pragma unroll
  for (int j = 0; j < 4; ++j) {
    const int k = k0 + j;
    const size_t dst = (size_t)(k >> 5) * (48 * 32) + (size_t)m * 32 + (k & 31);
    if (m < NMEM) {
      const float s = inv32[m];
      float w = mem[(size_t)m * DIM + k] * s;
      unsigned int u = __builtin_bit_cast(unsigned int, w);
      BH[dst] = (unsigned short)(u >> 16);
      float hf = __builtin_bit_cast(float, u & 0xFFFF0000u);
      float lo = w - hf;
      BL[dst] = (unsigned short)(__builtin_bit_cast(unsigned int, lo) >> 16);
    } else {
      BH[dst] = 0;
      BL[dst] = 0;
    }
  }
}

// ---------------- Kernel 2: MFMA sims + argmax + gather + x-copy ----------------
// Block = 256 thr = 4 independent waves (no barriers). Wave = 16 x-rows.
// Per K-eighth e (128 floats): LOAD all 16 rows (512B contiguous each, 16 in
// flight), CONSUME (512B-contiguous nt x-copy + ds_write, pitch-66 float2 ->
// worst 2-way bank conflicts = free), then 4 steps of {B-loads (1KB
// contiguous L2), A-frags from LDS, split, 12 MFMA}.
// C layout (m89-verified): lane holds D[(l>>4)*4+j][(l&15)+16*tile].
__global__ __launch_bounds__(256, 4) void k_main(const float* __restrict__ x,
                                                 const float* __restrict__ mem,
                                                 const unsigned short* __restrict__ BH,
                                                 const unsigned short* __restrict__ BL,
                                                 float* __restrict__ out_near,
                                                 float* __restrict__ out_x,
                                                 unsigned int* __restrict__ flagbits) {
  __shared__ vf2 xw8[4 * 16 * 66];     // 33 KB: wave w owns [w*1056, +1056); row pitch 66

  const int tid  = threadIdx.x;
  const int lane = tid & 63;
  const int w    = __builtin_amdgcn_readfirstlane(tid >> 6);
  const int row  = lane & 15;          // x-row within wave tile / m-col within tile
  const int kg   = lane >> 4;          // k-subslice group (0..3)
  const int rowbase = blockIdx.x * 64 + w * 16;

  const unsigned short* __restrict__ bp = BH + row * 32 + kg * 8;  // + T*1536 + tt*512
  const unsigned short* __restrict__ lp = BL + row * 32 + kg * 8;

  f4a acc[3];
#pragma unroll
  for (int t = 0; t < 3; ++t) acc[t] = (f4a){0.f, 0.f, 0.f, 0.f};
  float nx = 0.f;

  const int e0 = (blockIdx.x + w * 3) & 7;   // eighth-phase rotation (de-phasing)
  vf2* __restrict__ xw = xw8 + w * 1056;

#pragma unroll 1
  for (int ee = 0; ee < 8; ++ee) {
    const int e = (e0 + ee) & 7;
    // ---- stage eighth e: LOAD-ALL (16 x 512B, back-to-back) ... ----
    vf2 g[16];
#pragma unroll
    for (int r = 0; r < 16; ++r)
      g[r] = *(const vf2*)(x + (size_t)(rowbase + r) * DIM + e * 128 + lane * 2);
    // ---- ... THEN-CONSUME (nt x-copy + ds_write, retirement order) ----
#pragma unroll
    for (int r = 0; r < 16; ++r) {
      __builtin_nontemporal_store(g[r],
          (vf2*)(out_x + (size_t)(rowbase + r) * DIM + e * 128 + lane * 2));
      xw[r * 66 + lane] = g[r];
    }
    // ---- compute 4 K-steps of this eighth ----
#pragma unroll
    for (int tl = 0; tl < 4; ++tl) {
      const int T = e * 4 + tl;
      s8v bh[3], bl[3];                 // B first (issue order; L2, 1KB contiguous)
#pragma unroll
      for (int tt = 0; tt < 3; ++tt) {
        bh[tt] = *(const s8v*)(bp + (size_t)T * 1536 + tt * 512);
        bl[tt] = *(const s8v*)(lp + (size_t)T * 1536 + tt * 512);
      }
      // lane's 8 floats of step T: row `row`, float2 slots tl*16 + kg*4 + {0..3}
      const int fb = tl * 16 + kg * 4;
      vf2 p0 = xw[row * 66 + fb + 0];
      vf2 p1 = xw[row * 66 + fb + 1];
      vf2 p2 = xw[row * 66 + fb + 2];
      vf2 p3 = xw[row * 66 + fb + 3];
      nx = fmaf(p0.x, p0.x, fmaf(p0.y, p0.y, fmaf(p1.x, p1.x, fmaf(p1.y, p1.y, nx))));
      nx = fmaf(p2.x, p2.x, fmaf(p2.y, p2.y, fmaf(p3.x, p3.x, fmaf(p3.y, p3.y, nx))));
      FragU ah, al;
      {
        float fbuf[8] = {p0.x, p0.y, p1.x, p1.y, p2.x, p2.y, p3.x, p3.y};
#pragma unroll
        for (int p = 0; p < 4; ++p) {
          unsigned int u0 = __builtin_bit_cast(unsigned int, fbuf[2 * p]);
          unsigned int u1 = __builtin_bit_cast(unsigned int, fbuf[2 * p + 1]);
          ah.u[p] = (u1 & 0xFFFF0000u) | (u0 >> 16);
          float h0 = __builtin_bit_cast(float, u0 & 0xFFFF0000u);
          float h1 = __builtin_bit_cast(float, u1 & 0xFFFF0000u);
          float l0 = fbuf[2 * p] - h0;
          float l1 = fbuf[2 * p + 1] - h1;
          al.u[p] = (__builtin_bit_cast(unsigned int, l1) & 0xFFFF0000u) |
                    (__builtin_bit_cast(unsigned int, l0) >> 16);
        }
      }
#pragma unroll
      for (int tt = 0; tt < 3; ++tt) {
        acc[tt] = __builtin_amdgcn_mfma_f32_16x16x32_bf16(ah.v, bh[tt], acc[tt], 0, 0, 0);
        acc[tt] = __builtin_amdgcn_mfma_f32_16x16x32_bf16(ah.v, bl[tt], acc[tt], 0, 0, 0);
        acc[tt] = __builtin_amdgcn_mfma_f32_16x16x32_bf16(al.v, bh[tt], acc[tt], 0, 0, 0);
        acc[tt] = __builtin_amdgcn_mfma_f32_16x16x32_bf16(al.v, bl[tt], acc[tt], 0, 0, 0);
      }
    }
  }

  // ||x||^2: sum the 4 k-groups (lanes l, l^16, l^32, l^48 share row l&15)
  nx += __shfl_xor(nx, 16, 64);
  nx += __shfl_xor(nx, 32, 64);
  // now every lane: nx = ||x_{row=lane&15}||^2

  // per-lane top-2: lane holds sims for rows (l>>4)*4+j, m-cols (l&15)+16t
  float v1[4], v2[4];
  int   i1[4];
#pragma unroll
  for (int j = 0; j < 4; ++j) {
    float c0 = acc[0][j], c1 = acc[1][j];
    float c2 = (row < 8) ? acc[2][j] : -3.4e38f;   // cols 40-47 are pad
    float a1 = c0, a2 = -3.4e38f;
    int   ai = row;
    if (c1 > a1) { a2 = a1; a1 = c1; ai = row + 16; } else a2 = c1;
    if (c2 > a1) { a2 = a1; a1 = c2; ai = row + 32; } else if (c2 > a2) a2 = c2;
    v1[j] = a1; v2[j] = a2; i1[j] = ai;
  }
#pragma unroll
  for (int st = 1; st < 16; st <<= 1) {  // butterfly: 16 lanes of each group converge
#pragma unroll
    for (int j = 0; j < 4; ++j) {
      float o1 = __shfl_xor(v1[j], st, 64);
      float o2 = __shfl_xor(v2[j], st, 64);
      int   oi = __shfl_xor(i1[j], st, 64);
      if (o1 > v1[j]) { v2[j] = fmaxf(v1[j], o2); v1[j] = o1; i1[j] = oi; }
      else            { v2[j] = fmaxf(v2[j], o1); }           // tie -> gap 0 -> flagged
    }
  }
  // flags: group g (= lane>>4) holds rows 4g+j; nx fetched from row-owner lane
  const int g = lane >> 4;
  float nx0 = __shfl(nx, 4 * g + 0, 64);
  float nx1 = __shfl(nx, 4 * g + 1, 64);
  float nx2 = __shfl(nx, 4 * g + 2, 64);
  float nx3 = __shfl(nx, 4 * g + 3, 64);
  int fl0 = !((v1[0] - v2[0]) * rsqrtf(fmaxf(nx0, 1e-30f)) >= TAU);  // NaN-safe
  int fl1 = !((v1[1] - v2[1]) * rsqrtf(fmaxf(nx1, 1e-30f)) >= TAU);
  int fl2 = !((v1[2] - v2[2]) * rsqrtf(fmaxf(nx2, 1e-30f)) >= TAU);
  int fl3 = !((v1[3] - v2[3]) * rsqrtf(fmaxf(nx3, 1e-30f)) >= TAU);
  // redistribute (R18 pattern): shfl each flag register individually from the
  // row-owner group's lane 0, then select with the READING lane's j.
  const int srcl = 16 * ((lane & 15) >> 2);
  int f0 = __shfl(fl0, srcl, 64);
  int f1 = __shfl(fl1, srcl, 64);
  int f2 = __shfl(fl2, srcl, 64);
  int f3 = __shfl(fl3, srcl, 64);
  const int jsel = lane & 3;
  int flv = (jsel & 2) ? ((jsel & 1) ? f3 : f2) : ((jsel & 1) ? f1 : f0);
  unsigned long long bmask = __ballot(flv != 0);
  if (lane == 0) flagbits[blockIdx.x * 4 + w] = (unsigned int)(bmask & 0xFFFFull);

  // gather-copy memory[amax] -> out_near (16 rows/wave, coalesced nt full lines)
  // (i1[r&3] is compile-time-indexed on BOTH sides of the shfl -> correct)
  const vf4* __restrict__ m4 = (const vf4*)mem;
#pragma unroll
  for (int r = 0; r < 16; ++r) {
    int am = __shfl(i1[r & 3], 16 * (r >> 2), 64);
    am = __builtin_amdgcn_readfirstlane(am);
    const vf4* __restrict__ src = m4 + (size_t)am * (DIM / 4);
    vf4* __restrict__ dst = (vf4*)out_near + (size_t)(rowbase + r) * (DIM / 4);
#pragma unroll
    for (int j = 0; j < 4; ++j) {
      vf4 v = src[lane + 64 * j];
      __builtin_nontemporal_store(v, &dst[lane + 64 * j]);
    }
  }
}

// ---------------- Kernel 3: f64 re-resolution of razor-thin rows ----------------
__global__ __launch_bounds__(256) void k_refine(const float* __restrict__ x,
                                                const float* __restrict__ mem,
                                                const double* __restrict__ inv64,
                                                const unsigned int* __restrict__ flagbits,
                                                float* __restrict__ out_near) {
  unsigned int mask = flagbits[blockIdx.x];
  if (mask == 0u) return;                   // uniform; nearly all blocks exit
  const int tid = threadIdx.x;
  const int lane = tid & 63;
  const int wid = tid >> 6;
  __shared__ double bval[4];
  __shared__ int bidx[4];
  while (mask) {
    int r = __ffs(mask) - 1;
    mask &= (mask - 1u);
    int rrow = blockIdx.x * 16 + r;
    const float* __restrict__ xr = x + (size_t)rrow * DIM;
    double xd[16];
#pragma unroll
    for (int i = 0; i < 16; ++i) xd[i] = (double)xr[lane + 64 * i];
    double best = -1e300;
    int bi = 0;
    for (int q = 0; q < 10; ++q) {
      int m = wid * 10 + q;
      const float* __restrict__ mr = mem + (size_t)m * DIM;
      double s = 0.0;
#pragma unroll
      for (int i = 0; i < 16; ++i) s = fma(xd[i], (double)mr[lane + 64 * i], s);
#pragma unroll
      for (int off = 32; off > 0; off >>= 1) s += __shfl_xor(s, off, 64);
      double v = s * inv64[m];              // identical (bitwise) across lanes
      if (v > best) { best = v; bi = m; }   // strict > keeps lowest m on ties
    }
    if (lane == 0) { bval[wid] = best; bidx[wid] = bi; }
    __syncthreads();
    double gv = bval[0];
    int gi = bidx[0];
#pragma unroll
    for (int gg = 1; gg < 4; ++gg) {
      if (bval[gg] > gv) { gv = bval[gg]; gi = bidx[gg]; }
    }
    const float4* __restrict__ src = (const float4*)mem + (size_t)gi * (DIM / 4);
    float4* __restrict__ dst = (float4*)out_near + (size_t)rrow * (DIM / 4);
    dst[tid] = src[tid];                    // 256 x 16B = full row, coalesced
    __syncthreads();                        // LDS reuse guard for next flagged row
  }
}

extern "C" void kernel_launch(void* const* d_in, const int* in_sizes, int n_in,
                              void* d_out, int out_size, void* d_ws, size_t ws_size,
                              hipStream_t stream) {
  const float* x   = (const float*)d_in[0];
  const float* mem = (const float*)d_in[1];
  // d_in[2] = top_k (unused: reference only consumes idx[:,0], i.e. the argmax)

  const int n_rows = in_sizes[0] / DIM;          // 65536
  float* out_near = (float*)d_out;
  float* out_x    = (float*)d_out + (size_t)n_rows * DIM;

  double* inv64 = (double*)d_ws;
  float*  inv32 = (float*)((char*)d_ws + 320);
  unsigned int* flagbits = (unsigned int*)((char*)d_ws + 512);
  unsigned short* BH = (unsigned short*)((char*)d_ws + 32768);
  unsigned short* BL = (unsigned short*)((char*)d_ws + 131072);

  hipLaunchKernelGGL(k_norms, dim3(NMEM), dim3(64), 0, stream, mem, inv64, inv32);
  hipLaunchKernelGGL(k_prep,  dim3(48),   dim3(256), 0, stream, mem, inv32, BH, BL);
  hipLaunchKernelGGL(k_main,  dim3(n_rows / 64), dim3(256), 0, stream,
                     x, mem, BH, BL, out_near, out_x, flagbits);
  hipLaunchKernelGGL(k_refine, dim3(n_rows / 16), dim3(256), 0, stream,
                     x, mem, inv64, flagbits, out_near);
}

// Round 21
// 183.623 us; speedup vs baseline: 1.1362x; 1.1362x over previous
//
#include <hip/hip_runtime.h>

// Problem: nearest = memory[argmax_m cosine(x_row, memory_m)], plus copy of x.
//   x: 65536 x 1024 f32, memory: 40 x 1024 f32, out = [nearest | x-copy]
//
// R21 = R19 (188us best: all HBM instrs 1KB contiguous, zero barriers) +
// cross-quarter register pipelining with explicit vmcnt-order discipline:
// per quarter, issue B(steps0-3) FIRST, then consume g_cur (oldest -> its
// wait drains nothing newer), then load g_next (HBM), then compute 0-3
// (B older than g_next -> B-wait leaves g_next in flight), then B(4-7) +
// compute 4-7 (retires g_next ~800cy after issue ~ latency). Removes the
// ~900cy/quarter exposure R19 had at consume. R20 (512B chunks, 2x occ)
// regressed: contiguity > occupancy; LDS caps this shape at 2 waves/SIMD.
//
// d_ws layout (bytes):
//   [0,      320) : double inv64[40]
//   [320,    480) : float  inv32[40]
//   [512,  16896) : uint flagbits[4096]  (16-bit mask per 16-row wave)
//   [32768,131072): ushort BH[32][48][32] (bf16 hi of mem*inv32, step-major)
//   [131072,229376): ushort BL[32][48][32] (bf16 lo, step-major)

#define DIM 1024
#define NMEM 40

typedef float  vf4 __attribute__((ext_vector_type(4)));
typedef float  f4a __attribute__((ext_vector_type(4)));
typedef short  s8v __attribute__((ext_vector_type(8)));

union FragU { s8v v; unsigned int u[4]; };

constexpr float TAU = 2.5e-4f;   // normalized top-2 gap below which f64 re-resolve

// ---------------- Kernel 1: memory-row inverse norms (f32 + f64) ----------------
__global__ __launch_bounds__(64) void k_norms(const float* __restrict__ mem,
                                              double* __restrict__ inv64,
                                              float* __restrict__ inv32) {
  const int m = blockIdx.x;      // 40 blocks, 1 wave each
  const int lane = threadIdx.x;
  const float* __restrict__ row = mem + (size_t)m * DIM;
  double s = 0.0;
#pragma unroll
  for (int i = 0; i < DIM / 64; ++i) {
    double v = (double)row[lane + 64 * i];
    s = fma(v, v, s);
  }
#pragma unroll
  for (int off = 32; off > 0; off >>= 1) s += __shfl_xor(s, off, 64);
  if (lane == 0) {
    double n = sqrt(s);
    n = (n > 1e-8) ? n : 1e-8;
    inv64[m] = 1.0 / n;
    inv32[m] = (float)(1.0 / n);
  }
}

// ------------- Kernel 1b: split normalized memory -> step-major bf16 hi/lo -------------
__global__ __launch_bounds__(256) void k_prep(const float* __restrict__ mem,
                                              const float* __restrict__ inv32,
                                              unsigned short* __restrict__ BH,
                                              unsigned short* __restrict__ BL) {
  const int m = blockIdx.x;            // 0..47 (40 real + 8 zero-pad)
  const int k0 = threadIdx.x * 4;      // 1024/256 = 4 elems/thread
#pragma unroll
  for (int j = 0; j < 4; ++j) {
    const int k = k0 + j;
    const size_t dst = (size_t)(k >> 5) * (48 * 32) + (size_t)m * 32 + (k & 31);
    if (m < NMEM) {
      const float s = inv32[m];
      float w = mem[(size_t)m * DIM + k] * s;
      unsigned int u = __builtin_bit_cast(unsigned int, w);
      BH[dst] = (unsigned short)(u >> 16);
      float hf = __builtin_bit_cast(float, u & 0xFFFF0000u);
      float lo = w - hf;
      BL[dst] = (unsigned short)(__builtin_bit_cast(unsigned int, lo) >> 16);
    } else {
      BH[dst] = 0;
      BL[dst] = 0;
    }
  }
}

// ---------------- Kernel 2: MFMA sims + argmax + gather + x-copy ----------------
// Block = 256 thr = 4 independent waves (no barriers). Wave = 16 x-rows.
// C layout (m89-verified): lane holds D[(l>>4)*4+j][(l&15)+16*tile].
__global__ __launch_bounds__(256, 2) void k_main(const float* __restrict__ x,
                                                 const float* __restrict__ mem,
                                                 const unsigned short* __restrict__ BH,
                                                 const unsigned short* __restrict__ BL,
                                                 float* __restrict__ out_near,
                                                 float* __restrict__ out_x,
                                                 unsigned int* __restrict__ flagbits) {
  __shared__ vf4 xq4[4 * 16 * 64];     // exactly 64 KB: wave w owns [w*1024, +1024)

  const int tid  = threadIdx.x;
  const int lane = tid & 63;
  const int w    = __builtin_amdgcn_readfirstlane(tid >> 6);
  const int row  = lane & 15;          // x-row within wave tile / m-col within tile
  const int kg   = lane >> 4;          // k-subslice group (0..3)
  const int rowbase = blockIdx.x * 64 + w * 16;

  const unsigned short* __restrict__ bp = BH + row * 32 + kg * 8;  // + T*1536 + tt*512
  const unsigned short* __restrict__ lp = BL + row * 32 + kg * 8;

  f4a acc[3];
#pragma unroll
  for (int t = 0; t < 3; ++t) acc[t] = (f4a){0.f, 0.f, 0.f, 0.f};
  float nx = 0.f;

  const int q0 = (blockIdx.x + w) & 3;   // quarter-phase rotation (de-phasing)
  vf4* __restrict__ xw = xq4 + w * 1024;

  // prologue: load quarter q0's 16 rows (1KB contiguous each)
  vf4 g[16];
#pragma unroll
  for (int r = 0; r < 16; ++r)
    g[r] = *(const vf4*)(x + (size_t)(rowbase + r) * DIM + q0 * 256 + lane * 4);

#pragma unroll 1
  for (int qq = 0; qq < 4; ++qq) {
    const int q = (q0 + qq) & 3;
    // ---- (1) B-loads for steps 0-3, ISSUED FIRST (older than g_next) ----
    s8v bh[4][3], bl[4][3];
#pragma unroll
    for (int tl = 0; tl < 4; ++tl)
#pragma unroll
      for (int tt = 0; tt < 3; ++tt) {
        bh[tl][tt] = *(const s8v*)(bp + (size_t)(q * 8 + tl) * 1536 + tt * 512);
        bl[tl][tt] = *(const s8v*)(lp + (size_t)(q * 8 + tl) * 1536 + tt * 512);
      }
    // ---- (2) consume g_cur: nt x-copy + swizzled ds_write (g oldest: its
    //          wait drains nothing newer) ----
#pragma unroll
    for (int r = 0; r < 16; ++r) {
      __builtin_nontemporal_store(g[r],
          (vf4*)(out_x + (size_t)(rowbase + r) * DIM + q * 256 + lane * 4));
      xw[r * 64 + (lane ^ (r & 7))] = g[r];   // XOR-swizzled (conflict-min)
    }
    // ---- (3) load g_next (HBM; newer than B(0-3): stays in flight through
    //          compute 0-3) ----
    if (qq < 3) {
      const int qn = (q0 + qq + 1) & 3;
#pragma unroll
      for (int r = 0; r < 16; ++r)
        g[r] = *(const vf4*)(x + (size_t)(rowbase + r) * DIM + qn * 256 + lane * 4);
    }
    // ---- (4) compute steps 0-3 from preloaded B + LDS fragments ----
#pragma unroll
    for (int tl = 0; tl < 4; ++tl) {
      const int f = tl * 8 + kg * 2;
      vf4 a0 = xw[row * 64 + (f ^ (row & 7))];
      vf4 a1 = xw[row * 64 + ((f + 1) ^ (row & 7))];
      nx = fmaf(a0.x, a0.x, fmaf(a0.y, a0.y, fmaf(a0.z, a0.z, fmaf(a0.w, a0.w, nx))));
      nx = fmaf(a1.x, a1.x, fmaf(a1.y, a1.y, fmaf(a1.z, a1.z, fmaf(a1.w, a1.w, nx))));
      FragU ah, al;
      {
        float fb[8] = {a0.x, a0.y, a0.z, a0.w, a1.x, a1.y, a1.z, a1.w};
#pragma unroll
        for (int p = 0; p < 4; ++p) {
          unsigned int u0 = __builtin_bit_cast(unsigned int, fb[2 * p]);
          unsigned int u1 = __builtin_bit_cast(unsigned int, fb[2 * p + 1]);
          ah.u[p] = (u1 & 0xFFFF0000u) | (u0 >> 16);
          float h0 = __builtin_bit_cast(float, u0 & 0xFFFF0000u);
          float h1 = __builtin_bit_cast(float, u1 & 0xFFFF0000u);
          float l0 = fb[2 * p] - h0;
          float l1 = fb[2 * p + 1] - h1;
          al.u[p] = (__builtin_bit_cast(unsigned int, l1) & 0xFFFF0000u) |
                    (__builtin_bit_cast(unsigned int, l0) >> 16);
        }
      }
#pragma unroll
      for (int tt = 0; tt < 3; ++tt) {
        acc[tt] = __builtin_amdgcn_mfma_f32_16x16x32_bf16(ah.v, bh[tl][tt], acc[tt], 0, 0, 0);
        acc[tt] = __builtin_amdgcn_mfma_f32_16x16x32_bf16(ah.v, bl[tl][tt], acc[tt], 0, 0, 0);
        acc[tt] = __builtin_amdgcn_mfma_f32_16x16x32_bf16(al.v, bh[tl][tt], acc[tt], 0, 0, 0);
      }
      // 4th pass al*bl kept for bit-identical sims vs R19
#pragma unroll
      for (int tt = 0; tt < 3; ++tt)
        acc[tt] = __builtin_amdgcn_mfma_f32_16x16x32_bf16(al.v, bl[tl][tt], acc[tt], 0, 0, 0);
    }
    // ---- (5) B-loads for steps 4-7 (their wait retires g_next ~800cy after
    //          issue ~ latency -> mostly hidden) ----
#pragma unroll
    for (int tl = 0; tl < 4; ++tl)
#pragma unroll
      for (int tt = 0; tt < 3; ++tt) {
        bh[tl][tt] = *(const s8v*)(bp + (size_t)(q * 8 + 4 + tl) * 1536 + tt * 512);
        bl[tl][tt] = *(const s8v*)(lp + (size_t)(q * 8 + 4 + tl) * 1536 + tt * 512);
      }
    // ---- (6) compute steps 4-7 ----
#pragma unroll
    for (int tl = 0; tl < 4; ++tl) {
      const int f = (4 + tl) * 8 + kg * 2;
      vf4 a0 = xw[row * 64 + (f ^ (row & 7))];
      vf4 a1 = xw[row * 64 + ((f + 1) ^ (row & 7))];
      nx = fmaf(a0.x, a0.x, fmaf(a0.y, a0.y, fmaf(a0.z, a0.z, fmaf(a0.w, a0.w, nx))));
      nx = fmaf(a1.x, a1.x, fmaf(a1.y, a1.y, fmaf(a1.z, a1.z, fmaf(a1.w, a1.w, nx))));
      FragU ah, al;
      {
        float fb[8] = {a0.x, a0.y, a0.z, a0.w, a1.x, a1.y, a1.z, a1.w};
#pragma unroll
        for (int p = 0; p < 4; ++p) {
          unsigned int u0 = __builtin_bit_cast(unsigned int, fb[2 * p]);
          unsigned int u1 = __builtin_bit_cast(unsigned int, fb[2 * p + 1]);
          ah.u[p] = (u1 & 0xFFFF0000u) | (u0 >> 16);
          float h0 = __builtin_bit_cast(float, u0 & 0xFFFF0000u);
          float h1 = __builtin_bit_cast(float, u1 & 0xFFFF0000u);
          float l0 = fb[2 * p] - h0;
          float l1 = fb[2 * p + 1] - h1;
          al.u[p] = (__builtin_bit_cast(unsigned int, l1) & 0xFFFF0000u) |
                    (__builtin_bit_cast(unsigned int, l0) >> 16);
        }
      }
#pragma unroll
      for (int tt = 0; tt < 3; ++tt) {
        acc[tt] = __builtin_amdgcn_mfma_f32_16x16x32_bf16(ah.v, bh[tl][tt], acc[tt], 0, 0, 0);
        acc[tt] = __builtin_amdgcn_mfma_f32_16x16x32_bf16(ah.v, bl[tl][tt], acc[tt], 0, 0, 0);
        acc[tt] = __builtin_amdgcn_mfma_f32_16x16x32_bf16(al.v, bh[tl][tt], acc[tt], 0, 0, 0);
      }
#pragma unroll
      for (int tt = 0; tt < 3; ++tt)
        acc[tt] = __builtin_amdgcn_mfma_f32_16x16x32_bf16(al.v, bl[tl][tt], acc[tt], 0, 0, 0);
    }
  }

  // ||x||^2: sum the 4 k-groups (lanes l, l^16, l^32, l^48 share row l&15)
  nx += __shfl_xor(nx, 16, 64);
  nx += __shfl_xor(nx, 32, 64);

  // per-lane top-2: lane holds sims for rows (l>>4)*4+j, m-cols (l&15)+16t
  float v1[4], v2[4];
  int   i1[4];
#pragma unroll
  for (int j = 0; j < 4; ++j) {
    float c0 = acc[0][j], c1 = acc[1][j];
    float c2 = (row < 8) ? acc[2][j] : -3.4e38f;   // cols 40-47 are pad
    float a1 = c0, a2 = -3.4e38f;
    int   ai = row;
    if (c1 > a1) { a2 = a1; a1 = c1; ai = row + 16; } else a2 = c1;
    if (c2 > a1) { a2 = a1; a1 = c2; ai = row + 32; } else if (c2 > a2) a2 = c2;
    v1[j] = a1; v2[j] = a2; i1[j] = ai;
  }
#pragma unroll
  for (int st = 1; st < 16; st <<= 1) {  // butterfly: 16 lanes of each group converge
#pragma unroll
    for (int j = 0; j < 4; ++j) {
      float o1 = __shfl_xor(v1[j], st, 64);
      float o2 = __shfl_xor(v2[j], st, 64);
      int   oi = __shfl_xor(i1[j], st, 64);
      if (o1 > v1[j]) { v2[j] = fmaxf(v1[j], o2); v1[j] = o1; i1[j] = oi; }
      else            { v2[j] = fmaxf(v2[j], o1); }           // tie -> gap 0 -> flagged
    }
  }
  // flags: group g (= lane>>4) holds rows 4g+j; nx fetched from row-owner lane
  const int gidx = lane >> 4;
  float nx0 = __shfl(nx, 4 * gidx + 0, 64);
  float nx1 = __shfl(nx, 4 * gidx + 1, 64);
  float nx2 = __shfl(nx, 4 * gidx + 2, 64);
  float nx3 = __shfl(nx, 4 * gidx + 3, 64);
  int fl0 = !((v1[0] - v2[0]) * rsqrtf(fmaxf(nx0, 1e-30f)) >= TAU);  // NaN-safe
  int fl1 = !((v1[1] - v2[1]) * rsqrtf(fmaxf(nx1, 1e-30f)) >= TAU);
  int fl2 = !((v1[2] - v2[2]) * rsqrtf(fmaxf(nx2, 1e-30f)) >= TAU);
  int fl3 = !((v1[3] - v2[3]) * rsqrtf(fmaxf(nx3, 1e-30f)) >= TAU);
  // redistribute (R18 pattern): shfl each flag register individually, select
  // with the READING lane's j.
  const int srcl = 16 * ((lane & 15) >> 2);
  int f0 = __shfl(fl0, srcl, 64);
  int f1 = __shfl(fl1, srcl, 64);
  int f2 = __shfl(fl2, srcl, 64);
  int f3 = __shfl(fl3, srcl, 64);
  const int jsel = lane & 3;
  int flv = (jsel & 2) ? ((jsel & 1) ? f3 : f2) : ((jsel & 1) ? f1 : f0);
  unsigned long long bmask = __ballot(flv != 0);
  if (lane == 0) flagbits[blockIdx.x * 4 + w] = (unsigned int)(bmask & 0xFFFFull);

  // gather-copy memory[amax] -> out_near (16 rows/wave, coalesced nt full lines)
  const vf4* __restrict__ m4 = (const vf4*)mem;
#pragma unroll
  for (int r = 0; r < 16; ++r) {
    int am = __shfl(i1[r & 3], 16 * (r >> 2), 64);
    am = __builtin_amdgcn_readfirstlane(am);
    const vf4* __restrict__ src = m4 + (size_t)am * (DIM / 4);
    vf4* __restrict__ dst = (vf4*)out_near + (size_t)(rowbase + r) * (DIM / 4);
#pragma unroll
    for (int j = 0; j < 4; ++j) {
      vf4 v = src[lane + 64 * j];
      __builtin_nontemporal_store(v, &dst[lane + 64 * j]);
    }
  }
}

// ---------------- Kernel 3: f64 re-resolution of razor-thin rows ----------------
__global__ __launch_bounds__(256) void k_refine(const float* __restrict__ x,
                                                const float* __restrict__ mem,
                                                const double* __restrict__ inv64,
                                                const unsigned int* __restrict__ flagbits,
                                                float* __restrict__ out_near) {
  unsigned int mask = flagbits[blockIdx.x];
  if (mask == 0u) return;                   // uniform; nearly all blocks exit
  const int tid = threadIdx.x;
  const int lane = tid & 63;
  const int wid = tid >> 6;
  __shared__ double bval[4];
  __shared__ int bidx[4];
  while (mask) {
    int r = __ffs(mask) - 1;
    mask &= (mask - 1u);
    int rrow = blockIdx.x * 16 + r;
    const float* __restrict__ xr = x + (size_t)rrow * DIM;
    double xd[16];
#pragma unroll
    for (int i = 0; i < 16; ++i) xd[i] = (double)xr[lane + 64 * i];
    double best = -1e300;
    int bi = 0;
    for (int q = 0; q < 10; ++q) {
      int m = wid * 10 + q;
      const float* __restrict__ mr = mem + (size_t)m * DIM;
      double s = 0.0;
#pragma unroll
      for (int i = 0; i < 16; ++i) s = fma(xd[i], (double)mr[lane + 64 * i], s);
#pragma unroll
      for (int off = 32; off > 0; off >>= 1) s += __shfl_xor(s, off, 64);
      double v = s * inv64[m];              // identical (bitwise) across lanes
      if (v > best) { best = v; bi = m; }   // strict > keeps lowest m on ties
    }
    if (lane == 0) { bval[wid] = best; bidx[wid] = bi; }
    __syncthreads();
    double gv = bval[0];
    int gi = bidx[0];
#pragma unroll
    for (int gg = 1; gg < 4; ++gg) {
      if (bval[gg] > gv) { gv = bval[gg]; gi = bidx[gg]; }
    }
    const float4* __restrict__ src = (const float4*)mem + (size_t)gi * (DIM / 4);
    float4* __restrict__ dst = (float4*)out_near + (size_t)rrow * (DIM / 4);
    dst[tid] = src[tid];                    // 256 x 16B = full row, coalesced
    __syncthreads();                        // LDS reuse guard for next flagged row
  }
}

extern "C" void kernel_launch(void* const* d_in, const int* in_sizes, int n_in,
                              void* d_out, int out_size, void* d_ws, size_t ws_size,
                              hipStream_t stream) {
  const float* x   = (const float*)d_in[0];
  const float* mem = (const float*)d_in[1];
  // d_in[2] = top_k (unused: reference only consumes idx[:,0], i.e. the argmax)

  const int n_rows = in_sizes[0] / DIM;          // 65536
  float* out_near = (float*)d_out;
  float* out_x    = (float*)d_out + (size_t)n_rows * DIM;

  double* inv64 = (double*)d_ws;
  float*  inv32 = (float*)((char*)d_ws + 320);
  unsigned int* flagbits = (unsigned int*)((char*)d_ws + 512);
  unsigned short* BH = (unsigned short*)((char*)d_ws + 32768);
  unsigned short* BL = (unsigned short*)((char*)d_ws + 131072);

  hipLaunchKernelGGL(k_norms, dim3(NMEM), dim3(64), 0, stream, mem, inv64, inv32);
  hipLaunchKernelGGL(k_prep,  dim3(48),   dim3(256), 0, stream, mem, inv32, BH, BL);
  hipLaunchKernelGGL(k_main,  dim3(n_rows / 64), dim3(256), 0, stream,
                     x, mem, BH, BL, out_near, out_x, flagbits);
  hipLaunchKernelGGL(k_refine, dim3(n_rows / 16), dim3(256), 0, stream,
                     x, mem, inv64, flagbits, out_near);
}